// Round 1
// baseline (356.346 us; speedup 1.0000x reference)
//
#include <hip/hip_runtime.h>
#include <hip/hip_bf16.h>

typedef __hip_bfloat16 bf16;
typedef short bf16x8 __attribute__((ext_vector_type(8)));   // 8 bf16 = 16B (4 VGPRs)
typedef float f32x4 __attribute__((ext_vector_type(4)));

#define ND     40962
#define NUP    163842
#define NBATCH 2
#define NT     2561            // ceil(NUP/64)
#define BN_EPS 1e-5
#define SLOPE  0.2f

// ---- ws layout (bytes), all 256-aligned ----
#define OFF_W1P   0ull                      // 64*896*2  = 114688
#define OFF_W2P   114688ull                 // 64*448*2  = 57344
#define OFF_STATS 172032ull                 // sc[64]+sh[64] fp32 = 512
#define OFF_H     173056ull                 // h bf16: 2*40962*64*2 = 10486272
#define OFF_P2    (OFF_H + 2622464ull)      // p2 aliases h tail (h dead when used)
// partials alias OFF_H (h dead after k_xcat)
#define OFF_XCAT  10659328ull               // x_cat bf16: 2*163842*128*2 = 83887104 ; z1 aliases
#define OFF_Y     94546432ull               // y fp32: 2*163842*64*4 = 83887104
// total ≈ 178.4 MB

__device__ __forceinline__ void gload_lds16(const void* g, void* l) {
  __builtin_amdgcn_global_load_lds(
      (const __attribute__((address_space(1))) void*)g,
      (__attribute__((address_space(3))) void*)l, 16, 0, 0);
}

__device__ __forceinline__ float lrelu(float v) { return v >= 0.0f ? v : SLOPE * v; }

// ---------------- K0: permute + bf16-convert conv weights: f' = kk*C + c ----------------
__global__ __launch_bounds__(256) void k_permw(const float* __restrict__ w1,
                                               const float* __restrict__ w2,
                                               bf16* __restrict__ w1p, bf16* __restrict__ w2p) {
  int t = blockIdx.x * 256 + threadIdx.x;
  if (t < 64 * 896) {
    int o = t / 896, f = t % 896;
    int kk = f / 128, c = f % 128;
    w1p[t] = __float2bfloat16(w1[o * 896 + c * 7 + kk]);
  } else if (t < 64 * 896 + 64 * 448) {
    int idx = t - 64 * 896;
    int o = idx / 448, f = idx % 448;
    int kk = f / 64, c = f % 64;
    w2p[idx] = __float2bfloat16(w2[o * 448 + c * 7 + kk]);
  }
}

// ---------------- K1: h[b,n,o] = sum_c x1[b,c,n]*wfc[o,c] + bfc[o]  (bf16 out, node-major) ----
__global__ __launch_bounds__(256) void k_h(const float* __restrict__ x1,
                                           const float* __restrict__ wfc,
                                           const float* __restrict__ bfc,
                                           bf16* __restrict__ h) {
  __shared__ float wl[128 * 64];   // wl[c*64+o]
  __shared__ float bl[64];
  int tid = threadIdx.x, b = blockIdx.y;
  for (int i = tid; i < 8192; i += 256) { int o = i >> 7, c = i & 127; wl[c * 64 + o] = wfc[i]; }
  if (tid < 64) bl[tid] = bfc[tid];
  __syncthreads();
  int n = blockIdx.x * 256 + tid;
  int nc = n < ND ? n : ND - 1;
  float acc[64];
#pragma unroll
  for (int o = 0; o < 64; ++o) acc[o] = bl[o];
#pragma unroll 4
  for (int c = 0; c < 128; ++c) {
    float xv = x1[((size_t)b * 128 + c) * (size_t)ND + nc];
    const f32x4* wrow = (const f32x4*)(wl + c * 64);
#pragma unroll
    for (int og = 0; og < 16; ++og) {
      f32x4 wv = wrow[og];
      acc[og * 4 + 0] = fmaf(xv, wv[0], acc[og * 4 + 0]);
      acc[og * 4 + 1] = fmaf(xv, wv[1], acc[og * 4 + 1]);
      acc[og * 4 + 2] = fmaf(xv, wv[2], acc[og * 4 + 2]);
      acc[og * 4 + 3] = fmaf(xv, wv[3], acc[og * 4 + 3]);
    }
  }
  if (n < ND) {
    bf16* hp = h + ((size_t)b * ND + n) * 64;
#pragma unroll
    for (int og = 0; og < 8; ++og) {
      union { bf16x8 v; bf16 e[8]; } u;
#pragma unroll
      for (int j = 0; j < 8; ++j) u.e[j] = __float2bfloat16(acc[og * 8 + j]);
      ((bf16x8*)hp)[og] = u.v;
    }
  }
}

// ---------------- K2: x_cat[b,m,0:64] = 0.5*(h[n0]+h[n1]); x_cat[b,m,64:128] = x2[b,:,m] ------
__global__ __launch_bounds__(256) void k_xcat(const float* __restrict__ x2,
                                              const bf16* __restrict__ h,
                                              const int* __restrict__ upn,
                                              bf16* __restrict__ xcat) {
  __shared__ float tt[64][65];
  __shared__ int un[64][2];
  int tid = threadIdx.x, b = blockIdx.y;
  int m0 = blockIdx.x * 64;
#pragma unroll
  for (int i = 0; i < 16; ++i) {
    int c = i * 4 + (tid >> 6);
    int ml = tid & 63;
    int m = m0 + ml; if (m >= NUP) m = NUP - 1;
    tt[c][ml] = x2[((size_t)b * 64 + c) * (size_t)NUP + m];
  }
  if (tid < 128) {
    int ml = tid >> 1, w = tid & 1;
    int m = m0 + ml; if (m >= NUP) m = NUP - 1;
    un[ml][w] = upn[(size_t)m * 2 + w];
  }
  __syncthreads();
  int ln = tid >> 2, p = tid & 3;
  int m = m0 + ln;
  if (m >= NUP) return;
  bf16* dst = xcat + ((size_t)b * NUP + m) * 128;
  if (p < 2) {
    int c0 = p * 32;
    const bf16* h0 = h + ((size_t)b * ND + un[ln][0]) * 64 + c0;
    const bf16* h1 = h + ((size_t)b * ND + un[ln][1]) * 64 + c0;
#pragma unroll
    for (int q = 0; q < 4; ++q) {
      union { bf16x8 v; bf16 e[8]; } a, bb, o_;
      a.v = ((const bf16x8*)h0)[q];
      bb.v = ((const bf16x8*)h1)[q];
#pragma unroll
      for (int j = 0; j < 8; ++j)
        o_.e[j] = __float2bfloat16(0.5f * (__bfloat162float(a.e[j]) + __bfloat162float(bb.e[j])));
      ((bf16x8*)(dst + c0))[q] = o_.v;
    }
  } else {
    int c0 = (p - 2) * 32;
#pragma unroll
    for (int q = 0; q < 4; ++q) {
      union { bf16x8 v; bf16 e[8]; } o_;
#pragma unroll
      for (int j = 0; j < 8; ++j) o_.e[j] = __float2bfloat16(tt[c0 + q * 8 + j][ln]);
      ((bf16x8*)(dst + 64 + c0))[q] = o_.v;
    }
  }
}

// ---------------- K3: gathered conv (GEMM, K = 7*CIN), MFMA bf16, + BN partials --------------
// x node-major (B,NUP,CIN) bf16; wp (64, 7*CIN) bf16 with f' = kk*CIN + c; y (B,NUP,64) fp32.
template <int CIN>
__global__ __launch_bounds__(256) void k_conv(const bf16* __restrict__ x,
                                              const int* __restrict__ neigh,
                                              const bf16* __restrict__ wp,
                                              const float* __restrict__ bias,
                                              float* __restrict__ y,
                                              float* __restrict__ partials) {
  constexpr int CHA = CIN / 8;         // 16B chunks per row
  __shared__ bf16 lA[64 * CIN];
  __shared__ bf16 lW[64 * CIN];
  __shared__ int nb_[64 * 7];
  __shared__ float lred[4][2][64];
  int tid = threadIdx.x, b = blockIdx.y;
  int n0 = blockIdx.x * 64;
  int wv = tid >> 6, lane = tid & 63;

  for (int i = tid; i < 448; i += 256) {
    int nd = n0 + i / 7; if (nd >= NUP) nd = NUP - 1;
    nb_[i] = neigh[(size_t)nd * 7 + i % 7];
  }
  f32x4 acc[4];
#pragma unroll
  for (int ot = 0; ot < 4; ++ot) {
    float bv = bias[ot * 16 + (lane & 15)];
    acc[ot] = (f32x4){bv, bv, bv, bv};
  }
  __syncthreads();

  const bf16* xb = x + (size_t)b * NUP * CIN;
  for (int kk = 0; kk < 7; ++kk) {
    // stage A (gathered neighbor rows), swizzled source + linear LDS dest
#pragma unroll
    for (int i = 0; i < (64 * CHA) / 256; ++i) {
      int lin = i * 256 + tid;
      int row = lin / CHA, slot = lin % CHA;
      int gs = slot ^ (row & 7);
      int node = nb_[row * 7 + kk];
      gload_lds16(xb + (size_t)node * CIN + gs * 8, lA + (size_t)(i * 256 + wv * 64) * 8);
    }
    // stage W chunk for this neighbor
#pragma unroll
    for (int i = 0; i < (64 * CHA) / 256; ++i) {
      int lin = i * 256 + tid;
      int o = lin / CHA, slot = lin % CHA;
      int gs = slot ^ (o & 7);
      gload_lds16(wp + (size_t)o * (7 * CIN) + kk * CIN + gs * 8,
                  lW + (size_t)(i * 256 + wv * 64) * 8);
    }
    __syncthreads();   // drains vmcnt
#pragma unroll
    for (int ks = 0; ks < CIN / 32; ++ks) {
      int r = wv * 16 + (lane & 15);
      int g0 = ks * 4 + (lane >> 4);
      bf16x8 a = *(const bf16x8*)(lA + (size_t)(r * CHA + (g0 ^ (r & 7))) * 8);
#pragma unroll
      for (int ot = 0; ot < 4; ++ot) {
        int o = ot * 16 + (lane & 15);
        bf16x8 bb = *(const bf16x8*)(lW + (size_t)(o * CHA + (g0 ^ (o & 7))) * 8);
        acc[ot] = __builtin_amdgcn_mfma_f32_16x16x32_bf16(a, bb, acc[ot], 0, 0, 0);
      }
    }
    __syncthreads();
  }

  // store y + per-channel partial sums (valid nodes only)
  float s[4], q[4];
#pragma unroll
  for (int ot = 0; ot < 4; ++ot) {
    s[ot] = 0.0f; q[ot] = 0.0f;
    int o = ot * 16 + (lane & 15);
#pragma unroll
    for (int i = 0; i < 4; ++i) {
      int node = n0 + wv * 16 + (lane >> 4) * 4 + i;
      float v = acc[ot][i];
      if (node < NUP) {
        y[((size_t)b * NUP + node) * 64 + o] = v;
        s[ot] += v; q[ot] += v * v;
      }
    }
  }
#pragma unroll
  for (int ot = 0; ot < 4; ++ot) {
    s[ot] += __shfl_xor(s[ot], 16); s[ot] += __shfl_xor(s[ot], 32);
    q[ot] += __shfl_xor(q[ot], 16); q[ot] += __shfl_xor(q[ot], 32);
  }
  if (lane < 16) {
#pragma unroll
    for (int ot = 0; ot < 4; ++ot) {
      lred[wv][0][ot * 16 + lane] = s[ot];
      lred[wv][1][ot * 16 + lane] = q[ot];
    }
  }
  __syncthreads();
  if (tid < 128) {
    int which = tid >> 6, c = tid & 63;
    float p = lred[0][which][c] + lred[1][which][c] + lred[2][which][c] + lred[3][which][c];
    partials[((size_t)b * gridDim.x + blockIdx.x) * 128 + which * 64 + c] = p;
  }
}

// ---------------- K4a: tree-reduce partials (nblk x 128) -> (128 x 128) ----------------------
__global__ __launch_bounds__(256) void k_red1(const float* __restrict__ p, int nblk,
                                              float* __restrict__ p2) {
  int g = blockIdx.x * 2 + threadIdx.x / 128;
  int j = threadIdx.x & 127;
  float a = 0.0f;
  for (int r = g; r < nblk; r += 128) a += p[(size_t)r * 128 + j];
  p2[(size_t)g * 128 + j] = a;
}

// ---------------- K4b: finalize BN: sc = g*rsqrt(var+eps), sh = beta - mean*sc ---------------
__global__ __launch_bounds__(128) void k_stats(const float* __restrict__ p2,
                                               const float* __restrict__ g,
                                               const float* __restrict__ be,
                                               float* __restrict__ sc, float* __restrict__ sh) {
  __shared__ double red[128];
  int j = threadIdx.x;
  double a = 0.0;
  for (int r = 0; r < 128; ++r) a += (double)p2[r * 128 + j];
  red[j] = a;
  __syncthreads();
  if (j < 64) {
    double M = (double)NBATCH * (double)NUP;
    double mean = red[j] / M;
    double var = red[64 + j] / M - mean * mean;
    float s = g[j] * (float)(1.0 / sqrt(var + BN_EPS));
    sc[j] = s;
    sh[j] = be[j] - (float)mean * s;
  }
}

// ---------------- K5: z = bf16(lrelu(y*sc + sh))  (node-major) -------------------------------
__global__ __launch_bounds__(256) void k_bnapply(const float* __restrict__ y,
                                                 const float* __restrict__ sc,
                                                 const float* __restrict__ sh,
                                                 bf16* __restrict__ z) {
  __shared__ float ssc[64], ssh[64];
  int tid = threadIdx.x;
  if (tid < 64) { ssc[tid] = sc[tid]; ssh[tid] = sh[tid]; }
  __syncthreads();
  size_t e = ((size_t)blockIdx.x * 256 + tid) * 8;
  if (e >= (size_t)NBATCH * NUP * 64) return;
  int c0 = (int)(e & 63);
  f32x4 v0 = *(const f32x4*)(y + e);
  f32x4 v1 = *(const f32x4*)(y + e + 4);
  float vv[8] = {v0[0], v0[1], v0[2], v0[3], v1[0], v1[1], v1[2], v1[3]};
  union { bf16x8 v; bf16 el[8]; } o_;
#pragma unroll
  for (int j = 0; j < 8; ++j) {
    float zz = lrelu(fmaf(vv[j], ssc[c0 + j], ssh[c0 + j]));
    o_.el[j] = __float2bfloat16(zz);
  }
  *(bf16x8*)(z + e) = o_.v;
}

// ---------------- K8: out[b,c,n] = lrelu(y[b,n,c]*sc+sh)  (transpose to channel-major) -------
__global__ __launch_bounds__(256) void k_final(const float* __restrict__ y,
                                               const float* __restrict__ sc,
                                               const float* __restrict__ sh,
                                               float* __restrict__ out) {
  __shared__ float t[64][65];
  __shared__ float ssc[64], ssh[64];
  int tid = threadIdx.x, b = blockIdx.y;
  int n0 = blockIdx.x * 64;
  if (tid < 64) { ssc[tid] = sc[tid]; ssh[tid] = sh[tid]; }
  __syncthreads();
#pragma unroll
  for (int i = 0; i < 16; ++i) {
    int lin = i * 256 + tid;
    int nl = lin >> 6, c = lin & 63;
    int n = n0 + nl;
    float v = 0.0f;
    if (n < NUP) v = y[((size_t)b * NUP + n) * 64 + c];
    t[nl][c] = lrelu(fmaf(v, ssc[c], ssh[c]));
  }
  __syncthreads();
#pragma unroll
  for (int i = 0; i < 16; ++i) {
    int lin = i * 256 + tid;
    int c = lin >> 6, nl = lin & 63;
    int n = n0 + nl;
    if (n < NUP) out[((size_t)b * 64 + c) * (size_t)NUP + n] = t[nl][c];
  }
}

extern "C" void kernel_launch(void* const* d_in, const int* in_sizes, int n_in,
                              void* d_out, int out_size, void* d_ws, size_t ws_size,
                              hipStream_t stream) {
  const float* x1      = (const float*)d_in[0];
  const float* x2      = (const float*)d_in[1];
  const float* up_fc_w = (const float*)d_in[2];
  const float* up_fc_b = (const float*)d_in[3];
  const float* conv1_w = (const float*)d_in[4];
  const float* conv1_b = (const float*)d_in[5];
  const float* bn1_g   = (const float*)d_in[6];
  const float* bn1_b   = (const float*)d_in[7];
  const float* conv2_w = (const float*)d_in[8];
  const float* conv2_b = (const float*)d_in[9];
  const float* bn2_g   = (const float*)d_in[10];
  const float* bn2_b   = (const float*)d_in[11];
  const int* up_neigh  = (const int*)d_in[12];
  const int* conv_nei  = (const int*)d_in[13];

  char* ws = (char*)d_ws;
  bf16*  w1p  = (bf16*)(ws + OFF_W1P);
  bf16*  w2p  = (bf16*)(ws + OFF_W2P);
  float* sc   = (float*)(ws + OFF_STATS);
  float* sh   = sc + 64;
  bf16*  h    = (bf16*)(ws + OFF_H);
  float* part = (float*)(ws + OFF_H);      // aliases h (h dead after k_xcat)
  float* p2   = (float*)(ws + OFF_P2);
  bf16*  xcat = (bf16*)(ws + OFF_XCAT);
  bf16*  z1   = (bf16*)(ws + OFF_XCAT);    // aliases xcat (dead after conv1)
  float* y    = (float*)(ws + OFF_Y);
  float* out  = (float*)d_out;

  k_permw<<<336, 256, 0, stream>>>(conv1_w, conv2_w, w1p, w2p);
  k_h<<<dim3(161, 2), 256, 0, stream>>>(x1, up_fc_w, up_fc_b, h);
  k_xcat<<<dim3(NT, 2), 256, 0, stream>>>(x2, h, up_neigh, xcat);
  k_conv<128><<<dim3(NT, 2), 256, 0, stream>>>(xcat, conv_nei, w1p, conv1_b, y, part);
  k_red1<<<64, 256, 0, stream>>>(part, 2 * NT, p2);
  k_stats<<<1, 128, 0, stream>>>(p2, bn1_g, bn1_b, sc, sh);
  k_bnapply<<<10241, 256, 0, stream>>>(y, sc, sh, z1);
  k_conv<64><<<dim3(NT, 2), 256, 0, stream>>>(z1, conv_nei, w2p, conv2_b, y, part);
  k_red1<<<64, 256, 0, stream>>>(part, 2 * NT, p2);
  k_stats<<<1, 128, 0, stream>>>(p2, bn2_g, bn2_b, sc, sh);
  k_final<<<dim3(NT, 2), 256, 0, stream>>>(y, sc, sh, out);
}